// Round 18
// baseline (902.954 us; speedup 1.0000x reference)
//
#include <hip/hip_runtime.h>
#include <hip/hip_bf16.h>
#include <math.h>

#define TT 512   // T
#define BB 128   // B
#define EE 100   // embed dim
#define HH 128   // hidden
#define G4 512   // 4*H
#define K1 256   // 2*H

typedef __attribute__((ext_vector_type(8))) short bf16x8;
typedef __attribute__((ext_vector_type(4))) float f32x4;

__device__ inline unsigned short bf16_rne(float v) {
    __hip_bfloat16 h = __float2bfloat16(v);
    return *reinterpret_cast<unsigned short*>(&h);
}

__device__ inline void gload16(const void* g, void* l) {
    __builtin_amdgcn_global_load_lds(
        (const __attribute__((address_space(1))) void*)g,
        (__attribute__((address_space(3))) void*)l, 16, 0, 0);
}

// quad-scope DPP move (pure VALU)
template<int CTRL>
__device__ inline float dppf(float x) {
    int r = __builtin_amdgcn_update_dpp(0, __float_as_int(x), CTRL, 0xF, 0xF, true);
    return __int_as_float(r);
}

__device__ inline float sig_fast(float z) {
    return __builtin_amdgcn_rcpf(1.f + __expf(-z));
}

// ---- embedding -> xs2 bf16 hi, row = 128 shorts ---------------------------
__global__ void embed_cvt(const int* __restrict__ x, const float* __restrict__ emb,
                          unsigned short* __restrict__ xs2) {
    int row = blockIdx.x;          // t*B + b
    int k = threadIdx.x;           // 0..127
    int b = row & 127, t = row >> 7;
    int tok = x[b * TT + t];
    float v = (k < EE) ? emb[(size_t)tok * EE + k] : 0.f;
    xs2[(size_t)row * 128 + k] = bf16_rne(v);
}

// ---- weight -> bf16 hi, rows permuted to unit-major, gate order [i,g,f,o] --
__global__ void wcvt2(const float* __restrict__ srcf, const float* __restrict__ srcr,
                      int Kin, int Kp,
                      unsigned short* __restrict__ dstf, unsigned short* __restrict__ dstr) {
    const float* src = blockIdx.y ? srcr : srcf;
    unsigned short* dst = blockIdx.y ? dstr : dstf;
    int n = blockIdx.x;            // 0..511 (dst row)
    int k = threadIdx.x;           // 0..Kp-1
    int j = n & 3;
    int gate = ((j & 1) << 1) | (j >> 1);
    int r = gate * 128 + (n >> 2);
    float v = (k < Kin) ? src[(size_t)r * Kin + k] : 0.f;
    dst[(size_t)n * Kp + k] = bf16_rne(v);
}

// ---- biases for both layers: dst[layer*1024 + dir*512 + n] ---------------
__global__ void bias2(const float* __restrict__ bihf0, const float* __restrict__ bhhf0,
                      const float* __restrict__ bihr0, const float* __restrict__ bhhr0,
                      const float* __restrict__ bihf1, const float* __restrict__ bhhf1,
                      const float* __restrict__ bihr1, const float* __restrict__ bhhr1,
                      float* __restrict__ dst) {
    int n = blockIdx.x * 256 + threadIdx.x;   // 0..2047
    int layer = n >> 10;
    int d = (n >> 9) & 1, m = n & 511;
    int j = m & 3;
    int gate = ((j & 1) << 1) | (j >> 1);
    int src = gate * 128 + (m >> 2);
    const float* a = layer ? (d ? bihr1 : bihf1) : (d ? bihr0 : bihf0);
    const float* c = layer ? (d ? bhhr1 : bhhf1) : (d ? bhhr0 : bhhf0);
    dst[n] = a[src] + c[src];
}

// ---- pack all 4 whh -> wpk[which][u][k] (f32x4 of gates i,f,g,o) ----------
__global__ void whh_pack4(const float* __restrict__ w0f, const float* __restrict__ w0r,
                          const float* __restrict__ w1f, const float* __restrict__ w1r,
                          float* __restrict__ dstbase) {
    int which = blockIdx.y;
    const float* src = which == 0 ? w0f : which == 1 ? w0r : which == 2 ? w1f : w1r;
    float* dst = dstbase + (size_t)which * 128 * 128 * 4;
    int u = blockIdx.x;            // 0..127
    int k = threadIdx.x;           // 0..127
    float4 v;
    v.x = src[((size_t)(0 * 128 + u)) * 128 + k];
    v.y = src[((size_t)(1 * 128 + u)) * 128 + k];
    v.z = src[((size_t)(2 * 128 + u)) * 128 + k];
    v.w = src[((size_t)(3 * 128 + u)) * 128 + k];
    reinterpret_cast<float4*>(dst)[(size_t)u * 128 + k] = v;
}

// ---- MFMA GEMM: grid (8, TC), transposed epilogue, coalesced stores -------
template<int K2>
__global__ __launch_bounds__(256) void gemm_mfma(
    const unsigned short* __restrict__ A2,
    const unsigned short* __restrict__ W2cat,
    const float* __restrict__ biascat,
    float* __restrict__ Cf, float* __restrict__ Cr,
    int t_base)
{
    __shared__ bf16x8 As[1024];
    __shared__ bf16x8 Bs[1024];
    int tid = threadIdx.x;
    int s = blockIdx.y;
    int dir = blockIdx.x >> 2;
    int nBase = (blockIdx.x & 3) * 128;
    int t = dir ? (TT - 1 - t_base - s) : (t_base + s);
    float* C = dir ? Cr : Cf;
    const unsigned short* Abase = A2 + (size_t)t * BB * K2;
    const unsigned short* Wbase = W2cat + (size_t)(dir * 512 + nBase) * K2;
    int lane = tid & 63, wid = tid >> 6;
    int wr = wid >> 1, wc = wid & 1;
    int l15 = lane & 15, g = lane >> 4;

    f32x4 acc[4][4];
    const f32x4 z = {0.f, 0.f, 0.f, 0.f};
    #pragma unroll
    for (int i = 0; i < 4; ++i)
        #pragma unroll
        for (int j = 0; j < 4; ++j) acc[i][j] = z;

    for (int kt = 0; kt < K2 / 64; ++kt) {
        #pragma unroll
        for (int j = 0; j < 4; ++j) {
            int p = tid + j * 256;
            int row = p >> 3;
            int k16 = (p & 7) ^ (row & 7);
            size_t goff = (size_t)row * K2 + kt * 64 + k16 * 8;
            gload16(Abase + goff, &As[p]);
            gload16(Wbase + goff, &Bs[p]);
        }
        __syncthreads();
        #pragma unroll
        for (int ks = 0; ks < 2; ++ks) {
            bf16x8 af[4], bfr[4];
            #pragma unroll
            for (int i = 0; i < 4; ++i) {
                int arow = wr * 64 + i * 16 + l15;
                int abyte = arow * 128 + ((ks * 64 + g * 16) ^ ((arow & 7) << 4));
                af[i] = As[abyte >> 4];
                int brow = wc * 64 + i * 16 + l15;
                int bbyte = brow * 128 + ((ks * 64 + g * 16) ^ ((brow & 7) << 4));
                bfr[i] = Bs[bbyte >> 4];
            }
            #pragma unroll
            for (int i = 0; i < 4; ++i)
                #pragma unroll
                for (int j = 0; j < 4; ++j)
                    acc[i][j] = __builtin_amdgcn_mfma_f32_16x16x32_bf16(
                        af[i], bfr[j], acc[i][j], 0, 0, 0);
        }
        __syncthreads();
    }
    int l3 = l15 & 3;
    int cquad = l15 & 12;
    bool lb0 = (l15 & 1) != 0;
    bool lb1 = (l15 & 2) != 0;
    #pragma unroll
    for (int i = 0; i < 4; ++i) {
        int row = s * 128 + wr * 64 + i * 16 + g * 4 + l3;
        float* Crow = C + (size_t)row * G4;
        #pragma unroll
        for (int j = 0; j < 4; ++j) {
            int colb = nBase + wc * 64 + j * 16 + cquad;
            float4 bv = *reinterpret_cast<const float4*>(&biascat[dir * 512 + colb]);
            f32x4 v = acc[i][j];
            float t0 = dppf<0xB1>(v[1]);
            float t1 = dppf<0xB1>(v[0]);
            float t2 = dppf<0xB1>(v[3]);
            float t3 = dppf<0xB1>(v[2]);
            float T0 = lb0 ? t0 : v[0];
            float T1 = lb0 ? v[1] : t1;
            float T2 = lb0 ? t2 : v[2];
            float T3 = lb0 ? v[3] : t3;
            float s0 = dppf<0x4E>(T2);
            float s1 = dppf<0x4E>(T3);
            float s2 = dppf<0x4E>(T0);
            float s3 = dppf<0x4E>(T1);
            float W0 = lb1 ? s0 : T0;
            float W1 = lb1 ? s1 : T1;
            float W2 = lb1 ? T2 : s2;
            float W3 = lb1 ? T3 : s3;
            float4 outv = {W0 + bv.x, W1 + bv.y, W2 + bv.z, W3 + bv.w};
            *reinterpret_cast<float4*>(&Crow[colb]) = outv;
        }
    }
}

// ---- LSTM recurrence: OCT-per-unit (8 thr/unit, 1024-thr block) -----------
// Thread (u = tid>>3, o = tid&7) owns k-slice [16o,16o+16) of unit u's 4
// gates: 16 named f32x4 = 64 VGPR -> weights stay register-resident.
// Reduce: DPP ^1, ^2 (gate-scatter as before), then ^4 (0x141 then 0x1B).
__global__ __launch_bounds__(1024, 1) void lstm_chunk(
    const float* __restrict__ gxf,
    const float* __restrict__ gxr,
    const float* __restrict__ wpkf,
    const float* __restrict__ wpkr,
    float* __restrict__ h_state,
    float* __restrict__ c_state,
    unsigned short* __restrict__ out_x1,
    int t_base, int TC, int init)
{
    int blk = blockIdx.x;
    int dir = blk >> 7;
    int b   = blk & 127;
    const float* gx  = dir ? gxr : gxf;
    const float* wpk = dir ? wpkr : wpkf;
    int tid = threadIdx.x;
    int u = tid >> 3, o = tid & 7;

    // 16 named f32x4 weight registers: w_i = gates(i,f,g,o) at k = o*16+i
    const f32x4* wp4 = reinterpret_cast<const f32x4*>(wpk) + ((size_t)u * 128 + o * 16);
#define LW(i) const f32x4 w##i = wp4[i];
    LW(0)  LW(1)  LW(2)  LW(3)  LW(4)  LW(5)  LW(6)  LW(7)
    LW(8)  LW(9)  LW(10) LW(11) LW(12) LW(13) LW(14) LW(15)
#undef LW

    __shared__ float hb[2][160];
    int sbase = (dir * BB + b) * HH;
    int hslot = (u >> 5) * 40 + (u & 31);
    float c = init ? 0.f : c_state[sbase + u];
    float h = init ? 0.f : h_state[sbase + u];
    if (o == 0) hb[0][hslot] = h;
    __syncthreads();

    // h-read offset: k-slice [16o,16o+16) lives in quarter o>>1 at half o&1
    int roff = (o >> 1) * 40 + (o & 1) * 16;
    const size_t SSTR = (size_t)BB * G4;
    const float* gxrow = gx + b * G4 + 4 * u + (o & 3);  // gate col [i,g,f,o][o&3]
    bool odd1 = (o & 1) != 0;
    bool odd2 = (o & 2) != 0;
    float fq = ((o & 3) == 1) ? 2.f : 1.f;   // lane-gate map [i,g,f,o]
    float bq = ((o & 3) == 1) ? -1.f : 0.f;

    // 4-deep prefetch pipeline (named registers)
    float g0 = gxrow[0 * SSTR];
    float g1 = gxrow[1 * SSTR];
    float g2 = gxrow[2 * SSTR];
    float g3 = gxrow[3 * SSTR];

#define FMA1(W, HV, A) A = __builtin_elementwise_fma(W, f32x4{HV, HV, HV, HV}, A)
#define STEPB(J, GIN) { \
        constexpr int p2 = (J) & 1; \
        const float4* hp = reinterpret_cast<const float4*>(&hb[p2][roff]); \
        float4 hA = hp[0], hB = hp[1], hC = hp[2], hD = hp[3]; \
        f32x4 a0 = {0.f,0.f,0.f,0.f}, a1 = {0.f,0.f,0.f,0.f}; \
        FMA1(w0,  hA.x, a0); FMA1(w1,  hA.y, a1); \
        FMA1(w2,  hA.z, a0); FMA1(w3,  hA.w, a1); \
        FMA1(w4,  hB.x, a0); FMA1(w5,  hB.y, a1); \
        FMA1(w6,  hB.z, a0); FMA1(w7,  hB.w, a1); \
        FMA1(w8,  hC.x, a0); FMA1(w9,  hC.y, a1); \
        FMA1(w10, hC.z, a0); FMA1(w11, hC.w, a1); \
        FMA1(w12, hD.x, a0); FMA1(w13, hD.y, a1); \
        FMA1(w14, hD.z, a0); FMA1(w15, hD.w, a1); \
        f32x4 acc = a0 + a1; \
        float xs = acc.x + dppf<0xB1>(acc.x); \
        float ys = acc.y + dppf<0xB1>(acc.y); \
        float zs = acc.z + dppf<0xB1>(acc.z); \
        float ws = acc.w + dppf<0xB1>(acc.w); \
        float sa = odd1 ? zs : xs; \
        float sb = odd1 ? ws : ys; \
        float sa2 = sa + dppf<0x4E>(sa); \
        float sb2 = sb + dppf<0x4E>(sb); \
        float pd = odd2 ? sb2 : sa2; \
        float pre_dot = pd + dppf<0x1B>(dppf<0x141>(pd)); \
        float pre = pre_dot + (GIN); \
        float act = __builtin_fmaf(sig_fast(pre * fq), fq, bq); \
        float ig = dppf<0x00>(act); \
        float gg = dppf<0x55>(act); \
        float fg = dppf<0xAA>(act); \
        float og = dppf<0xFF>(act); \
        c = fg * c + ig * gg; \
        float th = __builtin_fmaf(2.f, sig_fast(2.f * c), -1.f); \
        h = og * th; \
        if (o == 0) { \
            hb[p2 ^ 1][hslot] = h; \
            if (out_x1) { \
                int sg = t_base + s + (J); \
                int tg = dir ? (TT - 1 - sg) : sg; \
                out_x1[((size_t)tg * BB + b) * 256 + dir * HH + u] = bf16_rne(h); \
            } \
        } \
        asm volatile("s_waitcnt lgkmcnt(0)" ::: "memory"); \
        __builtin_amdgcn_s_barrier(); \
        asm volatile("" ::: "memory"); \
    }

    for (int s = 0; s < TC; s += 4) {
        int nbase = (s + 4 <= TC - 4) ? (s + 4) : (TC - 4);
        float n0 = gxrow[(size_t)(nbase + 0) * SSTR];
        float n1 = gxrow[(size_t)(nbase + 1) * SSTR];
        float n2 = gxrow[(size_t)(nbase + 2) * SSTR];
        float n3 = gxrow[(size_t)(nbase + 3) * SSTR];
        STEPB(0, g0)
        STEPB(1, g1)
        STEPB(2, g2)
        STEPB(3, g3)
        g0 = n0; g1 = n1; g2 = n2; g3 = n3;
    }
#undef STEPB
#undef FMA1

    if (o == 0) {
        h_state[sbase + u] = h;
        c_state[sbase + u] = c;
    }
}

// ---- FC head --------------------------------------------------------------
__global__ void fc_kernel(const float* __restrict__ h_state,
                          const float* __restrict__ fc_w,
                          const float* __restrict__ fc_b,
                          float* __restrict__ out) {
    int tid = blockIdx.x * blockDim.x + threadIdx.x;
    if (tid >= BB * 3) return;
    int b = tid / 3;
    int c = tid % 3;
    float acc = 0.f;
    for (int j = 0; j < 256; ++j) {
        float v = (j < HH) ? h_state[((size_t)0 * BB + b) * HH + j]
                           : h_state[((size_t)1 * BB + b) * HH + (j - HH)];
        acc += v * fc_w[c * 256 + j];
    }
    out[b * 3 + c] = acc + fc_b[c];
}

extern "C" void kernel_launch(void* const* d_in, const int* in_sizes, int n_in,
                              void* d_out, int out_size, void* d_ws, size_t ws_size,
                              hipStream_t stream) {
    const int*   x        = (const int*)  d_in[0];
    const float* emb      = (const float*)d_in[1];
    const float* w_ih_l0  = (const float*)d_in[2];
    const float* w_hh_l0  = (const float*)d_in[3];
    const float* b_ih_l0  = (const float*)d_in[4];
    const float* b_hh_l0  = (const float*)d_in[5];
    const float* w_ih_l0r = (const float*)d_in[6];
    const float* w_hh_l0r = (const float*)d_in[7];
    const float* b_ih_l0r = (const float*)d_in[8];
    const float* b_hh_l0r = (const float*)d_in[9];
    const float* w_ih_l1  = (const float*)d_in[10];
    const float* w_hh_l1  = (const float*)d_in[11];
    const float* b_ih_l1  = (const float*)d_in[12];
    const float* b_hh_l1  = (const float*)d_in[13];
    const float* w_ih_l1r = (const float*)d_in[14];
    const float* w_hh_l1r = (const float*)d_in[15];
    const float* b_ih_l1r = (const float*)d_in[16];
    const float* b_hh_l1r = (const float*)d_in[17];
    const float* fc_w     = (const float*)d_in[18];
    const float* fc_b     = (const float*)d_in[19];
    float* out = (float*)d_out;
    (void)in_sizes; (void)n_in; (void)out_size;

    // ---- workspace layout ----
    size_t xs2_b   = (size_t)TT * BB * 128 * 2;         // 16.8 MB
    size_t x1_b    = (size_t)TT * BB * 256 * 2;         // 33.6 MB
    size_t w2l0_b  = (size_t)512 * 128 * 2;             // 128 KB
    size_t w2l1_b  = (size_t)512 * 256 * 2;             // 256 KB
    size_t bias_b  = (size_t)1024 * 4;
    size_t wpk_b   = (size_t)128 * 128 * 4 * 4;         // 256 KB each
    size_t state_b = (size_t)2 * BB * HH * 4;           // 128 KB
    size_t fixed = xs2_b + x1_b + 2 * w2l0_b + 2 * w2l1_b + 2 * bias_b
                 + 4 * wpk_b + 2 * state_b + 4096;
    int TC = 256;                              // L3-resident gx chunks (134 MB)
    while (TC > 8) {
        size_t chunk2 = (size_t)TC * BB * G4 * 4 * 2;
        if (fixed + chunk2 <= ws_size) break;
        TC >>= 1;
    }
    char* ws = (char*)d_ws;
    size_t off = 0;
    unsigned short* xs2   = (unsigned short*)(ws + off); off += xs2_b;
    unsigned short* x1_2  = (unsigned short*)(ws + off); off += x1_b;
    unsigned short* w2l0f = (unsigned short*)(ws + off); off += w2l0_b;  // fwd..
    unsigned short* w2l0r = (unsigned short*)(ws + off); off += w2l0_b;  // ..bwd
    unsigned short* w2l1f = (unsigned short*)(ws + off); off += w2l1_b;
    unsigned short* w2l1r = (unsigned short*)(ws + off); off += w2l1_b;
    float* biasl0  = (float*)(ws + off); off += bias_b;
    float* biasl1  = (float*)(ws + off); off += bias_b;
    float* wpk0f   = (float*)(ws + off); off += wpk_b;
    float* wpk0r   = (float*)(ws + off); off += wpk_b;
    float* wpk1f   = (float*)(ws + off); off += wpk_b;
    float* wpk1r   = (float*)(ws + off); off += wpk_b;
    float* h_state = (float*)(ws + off); off += state_b;
    float* c_state = (float*)(ws + off); off += state_b;
    float* gxf     = (float*)(ws + off); off += (size_t)TC * BB * G4 * 4;
    float* gxr     = (float*)(ws + off);

    int NC = TT / TC;

    // ---- precompute (5 launches) ----
    embed_cvt<<<TT * BB, 128, 0, stream>>>(x, emb, xs2);
    wcvt2<<<dim3(512, 2), 128, 0, stream>>>(w_ih_l0, w_ih_l0r, EE, 128, w2l0f, w2l0r);
    wcvt2<<<dim3(512, 2), 256, 0, stream>>>(w_ih_l1, w_ih_l1r, K1, 256, w2l1f, w2l1r);
    bias2<<<8, 256, 0, stream>>>(b_ih_l0, b_hh_l0, b_ih_l0r, b_hh_l0r,
                                 b_ih_l1, b_hh_l1, b_ih_l1r, b_hh_l1r, biasl0);
    whh_pack4<<<dim3(128, 4), 128, 0, stream>>>(w_hh_l0, w_hh_l0r, w_hh_l1, w_hh_l1r, wpk0f);

    // ---- layer 0: split, L3-resident gx chunks; lstm writes x1 ----
    for (int ci = 0; ci < NC; ++ci) {
        int t0 = ci * TC;
        gemm_mfma<128><<<dim3(8, TC), 256, 0, stream>>>(xs2, w2l0f, biasl0, gxf, gxr, t0);
        lstm_chunk<<<256, 1024, 0, stream>>>(gxf, gxr, wpk0f, wpk0r,
                                             h_state, c_state, x1_2, t0, TC, ci == 0);
    }
    // ---- layer 1: split, L3-resident gx chunks ----
    for (int ci = 0; ci < NC; ++ci) {
        int t0 = ci * TC;
        gemm_mfma<256><<<dim3(8, TC), 256, 0, stream>>>(x1_2, w2l1f, biasl1, gxf, gxr, t0);
        lstm_chunk<<<256, 1024, 0, stream>>>(gxf, gxr, wpk1f, wpk1r,
                                             h_state, c_state, nullptr, t0, TC, ci == 0);
    }
    // ---- FC head ----
    fc_kernel<<<2, 192, 0, stream>>>(h_state, fc_w, fc_b, out);
}

// Round 19
// 791.108 us; speedup vs baseline: 1.1414x; 1.1414x over previous
//
#include <hip/hip_runtime.h>
#include <hip/hip_bf16.h>
#include <math.h>

#define TT 512   // T
#define BB 128   // B
#define EE 100   // embed dim
#define HH 128   // hidden
#define G4 512   // 4*H
#define K1 256   // 2*H

typedef __attribute__((ext_vector_type(8))) short bf16x8;
typedef __attribute__((ext_vector_type(4))) float f32x4;

__device__ inline unsigned short bf16_rne(float v) {
    __hip_bfloat16 h = __float2bfloat16(v);
    return *reinterpret_cast<unsigned short*>(&h);
}

__device__ inline void gload16(const void* g, void* l) {
    __builtin_amdgcn_global_load_lds(
        (const __attribute__((address_space(1))) void*)g,
        (__attribute__((address_space(3))) void*)l, 16, 0, 0);
}

// quad-scope DPP move (pure VALU)
template<int CTRL>
__device__ inline float dppf(float x) {
    int r = __builtin_amdgcn_update_dpp(0, __float_as_int(x), CTRL, 0xF, 0xF, true);
    return __int_as_float(r);
}

__device__ inline float sig_fast(float z) {
    return __builtin_amdgcn_rcpf(1.f + __expf(-z));
}

// ---- embedding -> xs2 bf16 hi, row = 128 shorts ---------------------------
__global__ void embed_cvt(const int* __restrict__ x, const float* __restrict__ emb,
                          unsigned short* __restrict__ xs2) {
    int row = blockIdx.x;          // t*B + b
    int k = threadIdx.x;           // 0..127
    int b = row & 127, t = row >> 7;
    int tok = x[b * TT + t];
    float v = (k < EE) ? emb[(size_t)tok * EE + k] : 0.f;
    xs2[(size_t)row * 128 + k] = bf16_rne(v);
}

// ---- weight -> bf16 hi, rows permuted to unit-major, gate order [i,g,f,o] --
__global__ void wcvt2(const float* __restrict__ srcf, const float* __restrict__ srcr,
                      int Kin, int Kp,
                      unsigned short* __restrict__ dstf, unsigned short* __restrict__ dstr) {
    const float* src = blockIdx.y ? srcr : srcf;
    unsigned short* dst = blockIdx.y ? dstr : dstf;
    int n = blockIdx.x;            // 0..511 (dst row)
    int k = threadIdx.x;           // 0..Kp-1
    int j = n & 3;
    int gate = ((j & 1) << 1) | (j >> 1);
    int r = gate * 128 + (n >> 2);
    float v = (k < Kin) ? src[(size_t)r * Kin + k] : 0.f;
    dst[(size_t)n * Kp + k] = bf16_rne(v);
}

// ---- biases for both layers: dst[layer*1024 + dir*512 + n] ---------------
__global__ void bias2(const float* __restrict__ bihf0, const float* __restrict__ bhhf0,
                      const float* __restrict__ bihr0, const float* __restrict__ bhhr0,
                      const float* __restrict__ bihf1, const float* __restrict__ bhhf1,
                      const float* __restrict__ bihr1, const float* __restrict__ bhhr1,
                      float* __restrict__ dst) {
    int n = blockIdx.x * 256 + threadIdx.x;   // 0..2047
    int layer = n >> 10;
    int d = (n >> 9) & 1, m = n & 511;
    int j = m & 3;
    int gate = ((j & 1) << 1) | (j >> 1);
    int src = gate * 128 + (m >> 2);
    const float* a = layer ? (d ? bihr1 : bihf1) : (d ? bihr0 : bihf0);
    const float* c = layer ? (d ? bhhr1 : bhhf1) : (d ? bhhr0 : bhhf0);
    dst[n] = a[src] + c[src];
}

// ---- pack all 4 whh -> wpk[which][u][k] (f32x4 of gates i,f,g,o) ----------
__global__ void whh_pack4(const float* __restrict__ w0f, const float* __restrict__ w0r,
                          const float* __restrict__ w1f, const float* __restrict__ w1r,
                          float* __restrict__ dstbase) {
    int which = blockIdx.y;
    const float* src = which == 0 ? w0f : which == 1 ? w0r : which == 2 ? w1f : w1r;
    float* dst = dstbase + (size_t)which * 128 * 128 * 4;
    int u = blockIdx.x;            // 0..127
    int k = threadIdx.x;           // 0..127
    float4 v;
    v.x = src[((size_t)(0 * 128 + u)) * 128 + k];
    v.y = src[((size_t)(1 * 128 + u)) * 128 + k];
    v.z = src[((size_t)(2 * 128 + u)) * 128 + k];
    v.w = src[((size_t)(3 * 128 + u)) * 128 + k];
    reinterpret_cast<float4*>(dst)[(size_t)u * 128 + k] = v;
}

// ---- MFMA GEMM: grid (8, TC), transposed epilogue, coalesced stores -------
template<int K2>
__global__ __launch_bounds__(256) void gemm_mfma(
    const unsigned short* __restrict__ A2,
    const unsigned short* __restrict__ W2cat,
    const float* __restrict__ biascat,
    float* __restrict__ Cf, float* __restrict__ Cr,
    int t_base)
{
    __shared__ bf16x8 As[1024];
    __shared__ bf16x8 Bs[1024];
    int tid = threadIdx.x;
    int s = blockIdx.y;
    int dir = blockIdx.x >> 2;
    int nBase = (blockIdx.x & 3) * 128;
    int t = dir ? (TT - 1 - t_base - s) : (t_base + s);
    float* C = dir ? Cr : Cf;
    const unsigned short* Abase = A2 + (size_t)t * BB * K2;
    const unsigned short* Wbase = W2cat + (size_t)(dir * 512 + nBase) * K2;
    int lane = tid & 63, wid = tid >> 6;
    int wr = wid >> 1, wc = wid & 1;
    int l15 = lane & 15, g = lane >> 4;

    f32x4 acc[4][4];
    const f32x4 z = {0.f, 0.f, 0.f, 0.f};
    #pragma unroll
    for (int i = 0; i < 4; ++i)
        #pragma unroll
        for (int j = 0; j < 4; ++j) acc[i][j] = z;

    for (int kt = 0; kt < K2 / 64; ++kt) {
        #pragma unroll
        for (int j = 0; j < 4; ++j) {
            int p = tid + j * 256;
            int row = p >> 3;
            int k16 = (p & 7) ^ (row & 7);
            size_t goff = (size_t)row * K2 + kt * 64 + k16 * 8;
            gload16(Abase + goff, &As[p]);
            gload16(Wbase + goff, &Bs[p]);
        }
        __syncthreads();
        #pragma unroll
        for (int ks = 0; ks < 2; ++ks) {
            bf16x8 af[4], bfr[4];
            #pragma unroll
            for (int i = 0; i < 4; ++i) {
                int arow = wr * 64 + i * 16 + l15;
                int abyte = arow * 128 + ((ks * 64 + g * 16) ^ ((arow & 7) << 4));
                af[i] = As[abyte >> 4];
                int brow = wc * 64 + i * 16 + l15;
                int bbyte = brow * 128 + ((ks * 64 + g * 16) ^ ((brow & 7) << 4));
                bfr[i] = Bs[bbyte >> 4];
            }
            #pragma unroll
            for (int i = 0; i < 4; ++i)
                #pragma unroll
                for (int j = 0; j < 4; ++j)
                    acc[i][j] = __builtin_amdgcn_mfma_f32_16x16x32_bf16(
                        af[i], bfr[j], acc[i][j], 0, 0, 0);
        }
        __syncthreads();
    }
    int l3 = l15 & 3;
    int cquad = l15 & 12;
    bool lb0 = (l15 & 1) != 0;
    bool lb1 = (l15 & 2) != 0;
    #pragma unroll
    for (int i = 0; i < 4; ++i) {
        int row = s * 128 + wr * 64 + i * 16 + g * 4 + l3;
        float* Crow = C + (size_t)row * G4;
        #pragma unroll
        for (int j = 0; j < 4; ++j) {
            int colb = nBase + wc * 64 + j * 16 + cquad;
            float4 bv = *reinterpret_cast<const float4*>(&biascat[dir * 512 + colb]);
            f32x4 v = acc[i][j];
            float t0 = dppf<0xB1>(v[1]);
            float t1 = dppf<0xB1>(v[0]);
            float t2 = dppf<0xB1>(v[3]);
            float t3 = dppf<0xB1>(v[2]);
            float T0 = lb0 ? t0 : v[0];
            float T1 = lb0 ? v[1] : t1;
            float T2 = lb0 ? t2 : v[2];
            float T3 = lb0 ? v[3] : t3;
            float s0 = dppf<0x4E>(T2);
            float s1 = dppf<0x4E>(T3);
            float s2 = dppf<0x4E>(T0);
            float s3 = dppf<0x4E>(T1);
            float W0 = lb1 ? s0 : T0;
            float W1 = lb1 ? s1 : T1;
            float W2 = lb1 ? T2 : s2;
            float W3 = lb1 ? T3 : s3;
            float4 outv = {W0 + bv.x, W1 + bv.y, W2 + bv.z, W3 + bv.w};
            *reinterpret_cast<float4*>(&Crow[colb]) = outv;
        }
    }
}

// ---- LSTM recurrence: quad-per-unit, DPP cross-lane, asm-pinned weights ---
// launch_bounds (512,1): grid=256=#CUs so 1 block/CU is the real occupancy
// anyway; this lifts the VGPR cap so the 32 f32x4 whh registers stay RESIDENT
// (asm "+v" pin prevents spill-by-reload).
__global__ __launch_bounds__(512, 1) void lstm_chunk(
    const float* __restrict__ gxf,
    const float* __restrict__ gxr,
    const float* __restrict__ wpkf,
    const float* __restrict__ wpkr,
    float* __restrict__ h_state,
    float* __restrict__ c_state,
    unsigned short* __restrict__ out_x1,
    int t_base, int TC, int init)
{
    int blk = blockIdx.x;
    int dir = blk >> 7;
    int b   = blk & 127;
    const float* gx  = dir ? gxr : gxf;
    const float* wpk = dir ? wpkr : wpkf;
    int tid = threadIdx.x;
    int u = tid >> 2, q = tid & 3;

    const f32x4* wp4 = reinterpret_cast<const f32x4*>(wpk) + ((size_t)u * 128 + q * 32);
#define LW(i) f32x4 w##i = wp4[i];
    LW(0)  LW(1)  LW(2)  LW(3)  LW(4)  LW(5)  LW(6)  LW(7)
    LW(8)  LW(9)  LW(10) LW(11) LW(12) LW(13) LW(14) LW(15)
    LW(16) LW(17) LW(18) LW(19) LW(20) LW(21) LW(22) LW(23)
    LW(24) LW(25) LW(26) LW(27) LW(28) LW(29) LW(30) LW(31)
#undef LW
    // pin: values become asm outputs -> cannot be rematerialized by re-loading
    asm volatile("" : "+v"(w0), "+v"(w1), "+v"(w2), "+v"(w3),
                      "+v"(w4), "+v"(w5), "+v"(w6), "+v"(w7));
    asm volatile("" : "+v"(w8), "+v"(w9), "+v"(w10), "+v"(w11),
                      "+v"(w12), "+v"(w13), "+v"(w14), "+v"(w15));
    asm volatile("" : "+v"(w16), "+v"(w17), "+v"(w18), "+v"(w19),
                      "+v"(w20), "+v"(w21), "+v"(w22), "+v"(w23));
    asm volatile("" : "+v"(w24), "+v"(w25), "+v"(w26), "+v"(w27),
                      "+v"(w28), "+v"(w29), "+v"(w30), "+v"(w31));

    __shared__ float hb[2][160];
    int sbase = (dir * BB + b) * HH;
    int hslot = (u >> 5) * 40 + (u & 31);
    float c = init ? 0.f : c_state[sbase + u];
    float h = init ? 0.f : h_state[sbase + u];
    if (q == 0) hb[0][hslot] = h;
    __syncthreads();

    const size_t SSTR = (size_t)BB * G4;
    const float* gxrow = gx + b * G4 + tid;
    bool odd2 = (q & 2) != 0;
    bool oddq = (q & 1) != 0;
    float fq = (q == 1) ? 2.f : 1.f;
    float bq = (q == 1) ? -1.f : 0.f;

    float g0 = gxrow[0 * SSTR];
    float g1 = gxrow[1 * SSTR];
    float g2 = gxrow[2 * SSTR];
    float g3 = gxrow[3 * SSTR];

#define STEPB(J, GIN) { \
        constexpr int p2 = (J) & 1; \
        const float4* hb4 = reinterpret_cast<const float4*>(&hb[p2][40 * q]); \
        float4 hv0 = hb4[0], hv1 = hb4[1], hv2 = hb4[2], hv3 = hb4[3]; \
        float4 hv4 = hb4[4], hv5 = hb4[5], hv6 = hb4[6], hv7 = hb4[7]; \
        f32x4 a0 = {0.f,0.f,0.f,0.f}, a1 = {0.f,0.f,0.f,0.f}; \
        f32x4 a2 = {0.f,0.f,0.f,0.f}, a3 = {0.f,0.f,0.f,0.f}; \
        FM(0,1,2,3,hv0)    FM(4,5,6,7,hv1)    FM(8,9,10,11,hv2)  FM(12,13,14,15,hv3) \
        FM(16,17,18,19,hv4) FM(20,21,22,23,hv5) FM(24,25,26,27,hv6) FM(28,29,30,31,hv7) \
        f32x4 acc = (a0 + a1) + (a2 + a3); \
        float xs = acc.x + dppf<0xB1>(acc.x); \
        float ys = acc.y + dppf<0xB1>(acc.y); \
        float zs = acc.z + dppf<0xB1>(acc.z); \
        float ws = acc.w + dppf<0xB1>(acc.w); \
        float sa = oddq ? zs : xs; \
        float sb = oddq ? ws : ys; \
        float sa2 = sa + dppf<0x4E>(sa); \
        float sb2 = sb + dppf<0x4E>(sb); \
        float pre_dot = odd2 ? sb2 : sa2; \
        float pre = pre_dot + (GIN); \
        float act = __builtin_fmaf(sig_fast(pre * fq), fq, bq); \
        float ig = dppf<0x00>(act); \
        float gg = dppf<0x55>(act); \
        float fg = dppf<0xAA>(act); \
        float og = dppf<0xFF>(act); \
        c = fg * c + ig * gg; \
        float th = __builtin_fmaf(2.f, sig_fast(2.f * c), -1.f); \
        h = og * th; \
        if (q == 0) { \
            hb[p2 ^ 1][hslot] = h; \
            if (out_x1) { \
                int sg = t_base + s + (J); \
                int tg = dir ? (TT - 1 - sg) : sg; \
                out_x1[((size_t)tg * BB + b) * 256 + dir * HH + u] = bf16_rne(h); \
            } \
        } \
        asm volatile("s_waitcnt lgkmcnt(0)" ::: "memory"); \
        __builtin_amdgcn_s_barrier(); \
        asm volatile("" ::: "memory"); \
    }
#define FM(i0,i1,i2,i3,HV) { \
        f32x4 hh; \
        hh = f32x4{HV.x,HV.x,HV.x,HV.x}; a0 = __builtin_elementwise_fma(w##i0, hh, a0); \
        hh = f32x4{HV.y,HV.y,HV.y,HV.y}; a1 = __builtin_elementwise_fma(w##i1, hh, a1); \
        hh = f32x4{HV.z,HV.z,HV.z,HV.z}; a2 = __builtin_elementwise_fma(w##i2, hh, a2); \
        hh = f32x4{HV.w,HV.w,HV.w,HV.w}; a3 = __builtin_elementwise_fma(w##i3, hh, a3); }

    for (int s = 0; s < TC; s += 4) {
        int nbase = (s + 4 <= TC - 4) ? (s + 4) : (TC - 4);
        float n0 = gxrow[(size_t)(nbase + 0) * SSTR];
        float n1 = gxrow[(size_t)(nbase + 1) * SSTR];
        float n2 = gxrow[(size_t)(nbase + 2) * SSTR];
        float n3 = gxrow[(size_t)(nbase + 3) * SSTR];
        STEPB(0, g0)
        STEPB(1, g1)
        STEPB(2, g2)
        STEPB(3, g3)
        g0 = n0; g1 = n1; g2 = n2; g3 = n3;
    }
#undef FM
#undef STEPB

    if (q == 0) {
        h_state[sbase + u] = h;
        c_state[sbase + u] = c;
    }
}

// ---- FC head --------------------------------------------------------------
__global__ void fc_kernel(const float* __restrict__ h_state,
                          const float* __restrict__ fc_w,
                          const float* __restrict__ fc_b,
                          float* __restrict__ out) {
    int tid = blockIdx.x * blockDim.x + threadIdx.x;
    if (tid >= BB * 3) return;
    int b = tid / 3;
    int c = tid % 3;
    float acc = 0.f;
    for (int j = 0; j < 256; ++j) {
        float v = (j < HH) ? h_state[((size_t)0 * BB + b) * HH + j]
                           : h_state[((size_t)1 * BB + b) * HH + (j - HH)];
        acc += v * fc_w[c * 256 + j];
    }
    out[b * 3 + c] = acc + fc_b[c];
}

extern "C" void kernel_launch(void* const* d_in, const int* in_sizes, int n_in,
                              void* d_out, int out_size, void* d_ws, size_t ws_size,
                              hipStream_t stream) {
    const int*   x        = (const int*)  d_in[0];
    const float* emb      = (const float*)d_in[1];
    const float* w_ih_l0  = (const float*)d_in[2];
    const float* w_hh_l0  = (const float*)d_in[3];
    const float* b_ih_l0  = (const float*)d_in[4];
    const float* b_hh_l0  = (const float*)d_in[5];
    const float* w_ih_l0r = (const float*)d_in[6];
    const float* w_hh_l0r = (const float*)d_in[7];
    const float* b_ih_l0r = (const float*)d_in[8];
    const float* b_hh_l0r = (const float*)d_in[9];
    const float* w_ih_l1  = (const float*)d_in[10];
    const float* w_hh_l1  = (const float*)d_in[11];
    const float* b_ih_l1  = (const float*)d_in[12];
    const float* b_hh_l1  = (const float*)d_in[13];
    const float* w_ih_l1r = (const float*)d_in[14];
    const float* w_hh_l1r = (const float*)d_in[15];
    const float* b_ih_l1r = (const float*)d_in[16];
    const float* b_hh_l1r = (const float*)d_in[17];
    const float* fc_w     = (const float*)d_in[18];
    const float* fc_b     = (const float*)d_in[19];
    float* out = (float*)d_out;
    (void)in_sizes; (void)n_in; (void)out_size;

    // ---- workspace layout ----
    size_t xs2_b   = (size_t)TT * BB * 128 * 2;         // 16.8 MB
    size_t x1_b    = (size_t)TT * BB * 256 * 2;         // 33.6 MB
    size_t w2l0_b  = (size_t)512 * 128 * 2;             // 128 KB
    size_t w2l1_b  = (size_t)512 * 256 * 2;             // 256 KB
    size_t bias_b  = (size_t)1024 * 4;
    size_t wpk_b   = (size_t)128 * 128 * 4 * 4;         // 256 KB each
    size_t state_b = (size_t)2 * BB * HH * 4;           // 128 KB
    size_t fixed = xs2_b + x1_b + 2 * w2l0_b + 2 * w2l1_b + 2 * bias_b
                 + 4 * wpk_b + 2 * state_b + 4096;
    int TC = 256;                              // L3-resident gx chunks (134 MB)
    while (TC > 8) {
        size_t chunk2 = (size_t)TC * BB * G4 * 4 * 2;
        if (fixed + chunk2 <= ws_size) break;
        TC >>= 1;
    }
    char* ws = (char*)d_ws;
    size_t off = 0;
    unsigned short* xs2   = (unsigned short*)(ws + off); off += xs2_b;
    unsigned short* x1_2  = (unsigned short*)(ws + off); off += x1_b;
    unsigned short* w2l0f = (unsigned short*)(ws + off); off += w2l0_b;  // fwd..
    unsigned short* w2l0r = (unsigned short*)(ws + off); off += w2l0_b;  // ..bwd
    unsigned short* w2l1f = (unsigned short*)(ws + off); off += w2l1_b;
    unsigned short* w2l1r = (unsigned short*)(ws + off); off += w2l1_b;
    float* biasl0  = (float*)(ws + off); off += bias_b;
    float* biasl1  = (float*)(ws + off); off += bias_b;
    float* wpk0f   = (float*)(ws + off); off += wpk_b;
    float* wpk0r   = (float*)(ws + off); off += wpk_b;
    float* wpk1f   = (float*)(ws + off); off += wpk_b;
    float* wpk1r   = (float*)(ws + off); off += wpk_b;
    float* h_state = (float*)(ws + off); off += state_b;
    float* c_state = (float*)(ws + off); off += state_b;
    float* gxf     = (float*)(ws + off); off += (size_t)TC * BB * G4 * 4;
    float* gxr     = (float*)(ws + off);

    int NC = TT / TC;

    // ---- precompute (5 launches) ----
    embed_cvt<<<TT * BB, 128, 0, stream>>>(x, emb, xs2);
    wcvt2<<<dim3(512, 2), 128, 0, stream>>>(w_ih_l0, w_ih_l0r, EE, 128, w2l0f, w2l0r);
    wcvt2<<<dim3(512, 2), 256, 0, stream>>>(w_ih_l1, w_ih_l1r, K1, 256, w2l1f, w2l1r);
    bias2<<<8, 256, 0, stream>>>(b_ih_l0, b_hh_l0, b_ih_l0r, b_hh_l0r,
                                 b_ih_l1, b_hh_l1, b_ih_l1r, b_hh_l1r, biasl0);
    whh_pack4<<<dim3(128, 4), 128, 0, stream>>>(w_hh_l0, w_hh_l0r, w_hh_l1, w_hh_l1r, wpk0f);

    // ---- layer 0: split, L3-resident gx chunks; lstm writes x1 ----
    for (int ci = 0; ci < NC; ++ci) {
        int t0 = ci * TC;
        gemm_mfma<128><<<dim3(8, TC), 256, 0, stream>>>(xs2, w2l0f, biasl0, gxf, gxr, t0);
        lstm_chunk<<<256, 512, 0, stream>>>(gxf, gxr, wpk0f, wpk0r,
                                            h_state, c_state, x1_2, t0, TC, ci == 0);
    }
    // ---- layer 1: split, L3-resident gx chunks ----
    for (int ci = 0; ci < NC; ++ci) {
        int t0 = ci * TC;
        gemm_mfma<256><<<dim3(8, TC), 256, 0, stream>>>(x1_2, w2l1f, biasl1, gxf, gxr, t0);
        lstm_chunk<<<256, 512, 0, stream>>>(gxf, gxr, wpk1f, wpk1r,
                                            h_state, c_state, nullptr, t0, TC, ci == 0);
    }
    // ---- FC head ----
    fc_kernel<<<2, 192, 0, stream>>>(h_state, fc_w, fc_b, out);
}

// Round 20
// 754.914 us; speedup vs baseline: 1.1961x; 1.0479x over previous
//
#include <hip/hip_runtime.h>
#include <hip/hip_bf16.h>
#include <math.h>

#define TT 512   // T
#define BB 128   // B
#define EE 100   // embed dim
#define HH 128   // hidden
#define G4 512   // 4*H
#define K1 256   // 2*H

typedef __attribute__((ext_vector_type(8))) short bf16x8;
typedef __attribute__((ext_vector_type(4))) float f32x4;
typedef __attribute__((ext_vector_type(4))) _Float16 f16x4;

__device__ inline unsigned short bf16_rne(float v) {
    __hip_bfloat16 h = __float2bfloat16(v);
    return *reinterpret_cast<unsigned short*>(&h);
}

__device__ inline void gload16(const void* g, void* l) {
    __builtin_amdgcn_global_load_lds(
        (const __attribute__((address_space(1))) void*)g,
        (__attribute__((address_space(3))) void*)l, 16, 0, 0);
}

// quad-scope DPP move (pure VALU)
template<int CTRL>
__device__ inline float dppf(float x) {
    int r = __builtin_amdgcn_update_dpp(0, __float_as_int(x), CTRL, 0xF, 0xF, true);
    return __int_as_float(r);
}

__device__ inline float sig_fast(float z) {
    return __builtin_amdgcn_rcpf(1.f + __expf(-z));
}

// ---- embedding -> xs2 bf16 hi, row = 128 shorts ---------------------------
__global__ void embed_cvt(const int* __restrict__ x, const float* __restrict__ emb,
                          unsigned short* __restrict__ xs2) {
    int row = blockIdx.x;          // t*B + b
    int k = threadIdx.x;           // 0..127
    int b = row & 127, t = row >> 7;
    int tok = x[b * TT + t];
    float v = (k < EE) ? emb[(size_t)tok * EE + k] : 0.f;
    xs2[(size_t)row * 128 + k] = bf16_rne(v);
}

// ---- weight -> bf16 hi, rows permuted to unit-major, gate order [i,g,f,o] --
__global__ void wcvt2(const float* __restrict__ srcf, const float* __restrict__ srcr,
                      int Kin, int Kp,
                      unsigned short* __restrict__ dstf, unsigned short* __restrict__ dstr) {
    const float* src = blockIdx.y ? srcr : srcf;
    unsigned short* dst = blockIdx.y ? dstr : dstf;
    int n = blockIdx.x;            // 0..511 (dst row)
    int k = threadIdx.x;           // 0..Kp-1
    int j = n & 3;
    int gate = ((j & 1) << 1) | (j >> 1);
    int r = gate * 128 + (n >> 2);
    float v = (k < Kin) ? src[(size_t)r * Kin + k] : 0.f;
    dst[(size_t)n * Kp + k] = bf16_rne(v);
}

// ---- biases for both layers: dst[layer*1024 + dir*512 + n] ---------------
__global__ void bias2(const float* __restrict__ bihf0, const float* __restrict__ bhhf0,
                      const float* __restrict__ bihr0, const float* __restrict__ bhhr0,
                      const float* __restrict__ bihf1, const float* __restrict__ bhhf1,
                      const float* __restrict__ bihr1, const float* __restrict__ bhhr1,
                      float* __restrict__ dst) {
    int n = blockIdx.x * 256 + threadIdx.x;   // 0..2047
    int layer = n >> 10;
    int d = (n >> 9) & 1, m = n & 511;
    int j = m & 3;
    int gate = ((j & 1) << 1) | (j >> 1);
    int src = gate * 128 + (m >> 2);
    const float* a = layer ? (d ? bihr1 : bihf1) : (d ? bihr0 : bihf0);
    const float* c = layer ? (d ? bhhr1 : bhhf1) : (d ? bhhr0 : bhhf0);
    dst[n] = a[src] + c[src];
}

// ---- pack all 4 whh -> wpk[which][u][k] (f32x4 of gates i,f,g,o) ----------
__global__ void whh_pack4(const float* __restrict__ w0f, const float* __restrict__ w0r,
                          const float* __restrict__ w1f, const float* __restrict__ w1r,
                          float* __restrict__ dstbase) {
    int which = blockIdx.y;
    const float* src = which == 0 ? w0f : which == 1 ? w0r : which == 2 ? w1f : w1r;
    float* dst = dstbase + (size_t)which * 128 * 128 * 4;
    int u = blockIdx.x;            // 0..127
    int k = threadIdx.x;           // 0..127
    float4 v;
    v.x = src[((size_t)(0 * 128 + u)) * 128 + k];
    v.y = src[((size_t)(1 * 128 + u)) * 128 + k];
    v.z = src[((size_t)(2 * 128 + u)) * 128 + k];
    v.w = src[((size_t)(3 * 128 + u)) * 128 + k];
    reinterpret_cast<float4*>(dst)[(size_t)u * 128 + k] = v;
}

// ---- MFMA GEMM: grid (8, T), transposed epilogue, fp16 gx output ----------
template<int K2>
__global__ __launch_bounds__(256) void gemm_mfma(
    const unsigned short* __restrict__ A2,
    const unsigned short* __restrict__ W2cat,
    const float* __restrict__ biascat,
    _Float16* __restrict__ Cf, _Float16* __restrict__ Cr)
{
    __shared__ bf16x8 As[1024];
    __shared__ bf16x8 Bs[1024];
    int tid = threadIdx.x;
    int s = blockIdx.y;
    int dir = blockIdx.x >> 2;
    int nBase = (blockIdx.x & 3) * 128;
    int t = dir ? (TT - 1 - s) : s;
    _Float16* C = dir ? Cr : Cf;
    const unsigned short* Abase = A2 + (size_t)t * BB * K2;
    const unsigned short* Wbase = W2cat + (size_t)(dir * 512 + nBase) * K2;
    int lane = tid & 63, wid = tid >> 6;
    int wr = wid >> 1, wc = wid & 1;
    int l15 = lane & 15, g = lane >> 4;

    f32x4 acc[4][4];
    const f32x4 z = {0.f, 0.f, 0.f, 0.f};
    #pragma unroll
    for (int i = 0; i < 4; ++i)
        #pragma unroll
        for (int j = 0; j < 4; ++j) acc[i][j] = z;

    for (int kt = 0; kt < K2 / 64; ++kt) {
        #pragma unroll
        for (int j = 0; j < 4; ++j) {
            int p = tid + j * 256;
            int row = p >> 3;
            int k16 = (p & 7) ^ (row & 7);
            size_t goff = (size_t)row * K2 + kt * 64 + k16 * 8;
            gload16(Abase + goff, &As[p]);
            gload16(Wbase + goff, &Bs[p]);
        }
        __syncthreads();
        #pragma unroll
        for (int ks = 0; ks < 2; ++ks) {
            bf16x8 af[4], bfr[4];
            #pragma unroll
            for (int i = 0; i < 4; ++i) {
                int arow = wr * 64 + i * 16 + l15;
                int abyte = arow * 128 + ((ks * 64 + g * 16) ^ ((arow & 7) << 4));
                af[i] = As[abyte >> 4];
                int brow = wc * 64 + i * 16 + l15;
                int bbyte = brow * 128 + ((ks * 64 + g * 16) ^ ((brow & 7) << 4));
                bfr[i] = Bs[bbyte >> 4];
            }
            #pragma unroll
            for (int i = 0; i < 4; ++i)
                #pragma unroll
                for (int j = 0; j < 4; ++j)
                    acc[i][j] = __builtin_amdgcn_mfma_f32_16x16x32_bf16(
                        af[i], bfr[j], acc[i][j], 0, 0, 0);
        }
        __syncthreads();
    }
    int l3 = l15 & 3;
    int cquad = l15 & 12;
    bool lb0 = (l15 & 1) != 0;
    bool lb1 = (l15 & 2) != 0;
    #pragma unroll
    for (int i = 0; i < 4; ++i) {
        int row = s * 128 + wr * 64 + i * 16 + g * 4 + l3;
        _Float16* Crow = C + (size_t)row * G4;
        #pragma unroll
        for (int j = 0; j < 4; ++j) {
            int colb = nBase + wc * 64 + j * 16 + cquad;
            float4 bv = *reinterpret_cast<const float4*>(&biascat[dir * 512 + colb]);
            f32x4 v = acc[i][j];
            float t0 = dppf<0xB1>(v[1]);
            float t1 = dppf<0xB1>(v[0]);
            float t2 = dppf<0xB1>(v[3]);
            float t3 = dppf<0xB1>(v[2]);
            float T0 = lb0 ? t0 : v[0];
            float T1 = lb0 ? v[1] : t1;
            float T2 = lb0 ? t2 : v[2];
            float T3 = lb0 ? v[3] : t3;
            float s0 = dppf<0x4E>(T2);
            float s1 = dppf<0x4E>(T3);
            float s2 = dppf<0x4E>(T0);
            float s3 = dppf<0x4E>(T1);
            float W0 = lb1 ? s0 : T0;
            float W1 = lb1 ? s1 : T1;
            float W2 = lb1 ? T2 : s2;
            float W3 = lb1 ? T3 : s3;
            f16x4 outv = { (_Float16)(W0 + bv.x), (_Float16)(W1 + bv.y),
                           (_Float16)(W2 + bv.z), (_Float16)(W3 + bv.w) };
            *reinterpret_cast<f16x4*>(&Crow[colb]) = outv;
        }
    }
}

// ---- LSTM recurrence: quad-per-unit, DPP cross-lane, fp16 gin, TC=512 -----
__global__ __launch_bounds__(512, 1) void lstm_chunk(
    const _Float16* __restrict__ gxf,     // (T*B, 512) fp16 unit-major [i,g,f,o]
    const _Float16* __restrict__ gxr,
    const float* __restrict__ wpkf,
    const float* __restrict__ wpkr,
    float* __restrict__ h_state,
    float* __restrict__ c_state,
    unsigned short* __restrict__ out_x1,
    float* __restrict__ hlast)
{
    int blk = blockIdx.x;
    int dir = blk >> 7;
    int b   = blk & 127;
    const _Float16* gx = dir ? gxr : gxf;
    const float* wpk = dir ? wpkr : wpkf;
    int tid = threadIdx.x;
    int u = tid >> 2, q = tid & 3;

    const f32x4* wp4 = reinterpret_cast<const f32x4*>(wpk) + ((size_t)u * 128 + q * 32);
#define LW(i) const f32x4 w##i = wp4[i];
    LW(0)  LW(1)  LW(2)  LW(3)  LW(4)  LW(5)  LW(6)  LW(7)
    LW(8)  LW(9)  LW(10) LW(11) LW(12) LW(13) LW(14) LW(15)
    LW(16) LW(17) LW(18) LW(19) LW(20) LW(21) LW(22) LW(23)
    LW(24) LW(25) LW(26) LW(27) LW(28) LW(29) LW(30) LW(31)
#undef LW

    __shared__ float hb[2][160];
    int sbase = (dir * BB + b) * HH;
    int hslot = (u >> 5) * 40 + (u & 31);
    float c = 0.f;
    float h = 0.f;
    if (q == 0) hb[0][hslot] = 0.f;
    __syncthreads();

    const size_t SSTR = (size_t)BB * G4;
    const _Float16* gxrow = gx + b * G4 + tid;
    bool odd2 = (q & 2) != 0;
    bool oddq = (q & 1) != 0;
    float fq = (q == 1) ? 2.f : 1.f;
    float bq = (q == 1) ? -1.f : 0.f;

    float g0 = (float)gxrow[0 * SSTR];
    float g1 = (float)gxrow[1 * SSTR];
    float g2 = (float)gxrow[2 * SSTR];
    float g3 = (float)gxrow[3 * SSTR];

#define STEPB(J, GIN) { \
        constexpr int p2 = (J) & 1; \
        const float4* hb4 = reinterpret_cast<const float4*>(&hb[p2][40 * q]); \
        float4 hv0 = hb4[0], hv1 = hb4[1], hv2 = hb4[2], hv3 = hb4[3]; \
        float4 hv4 = hb4[4], hv5 = hb4[5], hv6 = hb4[6], hv7 = hb4[7]; \
        f32x4 a0 = {0.f,0.f,0.f,0.f}, a1 = {0.f,0.f,0.f,0.f}; \
        f32x4 a2 = {0.f,0.f,0.f,0.f}, a3 = {0.f,0.f,0.f,0.f}; \
        FM(0,1,2,3,hv0)    FM(4,5,6,7,hv1)    FM(8,9,10,11,hv2)  FM(12,13,14,15,hv3) \
        FM(16,17,18,19,hv4) FM(20,21,22,23,hv5) FM(24,25,26,27,hv6) FM(28,29,30,31,hv7) \
        f32x4 acc = (a0 + a1) + (a2 + a3); \
        float xs = acc.x + dppf<0xB1>(acc.x); \
        float ys = acc.y + dppf<0xB1>(acc.y); \
        float zs = acc.z + dppf<0xB1>(acc.z); \
        float ws = acc.w + dppf<0xB1>(acc.w); \
        float sa = oddq ? zs : xs; \
        float sb = oddq ? ws : ys; \
        float sa2 = sa + dppf<0x4E>(sa); \
        float sb2 = sb + dppf<0x4E>(sb); \
        float pre_dot = odd2 ? sb2 : sa2; \
        float pre = pre_dot + (GIN); \
        float act = __builtin_fmaf(sig_fast(pre * fq), fq, bq); \
        float ig = dppf<0x00>(act); \
        float gg = dppf<0x55>(act); \
        float fg = dppf<0xAA>(act); \
        float og = dppf<0xFF>(act); \
        c = fg * c + ig * gg; \
        float th = __builtin_fmaf(2.f, sig_fast(2.f * c), -1.f); \
        h = og * th; \
        if (q == 0) { \
            hb[p2 ^ 1][hslot] = h; \
            if (out_x1) { \
                int sg = s + (J); \
                int tg = dir ? (TT - 1 - sg) : sg; \
                out_x1[((size_t)tg * BB + b) * 256 + dir * HH + u] = bf16_rne(h); \
            } \
        } \
        asm volatile("s_waitcnt lgkmcnt(0)" ::: "memory"); \
        __builtin_amdgcn_s_barrier(); \
        asm volatile("" ::: "memory"); \
    }
#define FM(i0,i1,i2,i3,HV) { \
        f32x4 hh; \
        hh = f32x4{HV.x,HV.x,HV.x,HV.x}; a0 = __builtin_elementwise_fma(w##i0, hh, a0); \
        hh = f32x4{HV.y,HV.y,HV.y,HV.y}; a1 = __builtin_elementwise_fma(w##i1, hh, a1); \
        hh = f32x4{HV.z,HV.z,HV.z,HV.z}; a2 = __builtin_elementwise_fma(w##i2, hh, a2); \
        hh = f32x4{HV.w,HV.w,HV.w,HV.w}; a3 = __builtin_elementwise_fma(w##i3, hh, a3); }

    for (int s = 0; s < TT; s += 4) {
        int nbase = (s + 4 <= TT - 4) ? (s + 4) : (TT - 4);
        float n0 = (float)gxrow[(size_t)(nbase + 0) * SSTR];
        float n1 = (float)gxrow[(size_t)(nbase + 1) * SSTR];
        float n2 = (float)gxrow[(size_t)(nbase + 2) * SSTR];
        float n3 = (float)gxrow[(size_t)(nbase + 3) * SSTR];
        STEPB(0, g0)
        STEPB(1, g1)
        STEPB(2, g2)
        STEPB(3, g3)
        g0 = n0; g1 = n1; g2 = n2; g3 = n3;
    }
#undef FM
#undef STEPB

    if (q == 0) {
        if (hlast) hlast[sbase + u] = h;
        h_state[sbase + u] = h;
        c_state[sbase + u] = c;
    }
}

// ---- FC head --------------------------------------------------------------
__global__ void fc_kernel(const float* __restrict__ h_state,
                          const float* __restrict__ fc_w,
                          const float* __restrict__ fc_b,
                          float* __restrict__ out) {
    int tid = blockIdx.x * blockDim.x + threadIdx.x;
    if (tid >= BB * 3) return;
    int b = tid / 3;
    int c = tid % 3;
    float acc = 0.f;
    for (int j = 0; j < 256; ++j) {
        float v = (j < HH) ? h_state[((size_t)0 * BB + b) * HH + j]
                           : h_state[((size_t)1 * BB + b) * HH + (j - HH)];
        acc += v * fc_w[c * 256 + j];
    }
    out[b * 3 + c] = acc + fc_b[c];
}

extern "C" void kernel_launch(void* const* d_in, const int* in_sizes, int n_in,
                              void* d_out, int out_size, void* d_ws, size_t ws_size,
                              hipStream_t stream) {
    const int*   x        = (const int*)  d_in[0];
    const float* emb      = (const float*)d_in[1];
    const float* w_ih_l0  = (const float*)d_in[2];
    const float* w_hh_l0  = (const float*)d_in[3];
    const float* b_ih_l0  = (const float*)d_in[4];
    const float* b_hh_l0  = (const float*)d_in[5];
    const float* w_ih_l0r = (const float*)d_in[6];
    const float* w_hh_l0r = (const float*)d_in[7];
    const float* b_ih_l0r = (const float*)d_in[8];
    const float* b_hh_l0r = (const float*)d_in[9];
    const float* w_ih_l1  = (const float*)d_in[10];
    const float* w_hh_l1  = (const float*)d_in[11];
    const float* b_ih_l1  = (const float*)d_in[12];
    const float* b_hh_l1  = (const float*)d_in[13];
    const float* w_ih_l1r = (const float*)d_in[14];
    const float* w_hh_l1r = (const float*)d_in[15];
    const float* b_ih_l1r = (const float*)d_in[16];
    const float* b_hh_l1r = (const float*)d_in[17];
    const float* fc_w     = (const float*)d_in[18];
    const float* fc_b     = (const float*)d_in[19];
    float* out = (float*)d_out;
    (void)in_sizes; (void)n_in; (void)out_size; (void)ws_size;

    // ---- workspace layout (~187 MB) ----
    size_t xs2_b   = (size_t)TT * BB * 128 * 2;         // 16.8 MB
    size_t x1_b    = (size_t)TT * BB * 256 * 2;         // 33.6 MB
    size_t w2l0_b  = (size_t)512 * 128 * 2;             // 128 KB
    size_t w2l1_b  = (size_t)512 * 256 * 2;             // 256 KB
    size_t bias_b  = (size_t)1024 * 4;
    size_t wpk_b   = (size_t)128 * 128 * 4 * 4;         // 256 KB each
    size_t state_b = (size_t)2 * BB * HH * 4;           // 128 KB
    size_t gx_b    = (size_t)TT * BB * G4 * 2;          // 67.1 MB (fp16)
    char* ws = (char*)d_ws;
    size_t off = 0;
    unsigned short* xs2   = (unsigned short*)(ws + off); off += xs2_b;
    unsigned short* x1_2  = (unsigned short*)(ws + off); off += x1_b;
    unsigned short* w2l0f = (unsigned short*)(ws + off); off += w2l0_b;  // fwd..
    unsigned short* w2l0r = (unsigned short*)(ws + off); off += w2l0_b;  // ..bwd
    unsigned short* w2l1f = (unsigned short*)(ws + off); off += w2l1_b;
    unsigned short* w2l1r = (unsigned short*)(ws + off); off += w2l1_b;
    float* biasl0  = (float*)(ws + off); off += bias_b;
    float* biasl1  = (float*)(ws + off); off += bias_b;
    float* wpk0f   = (float*)(ws + off); off += wpk_b;
    float* wpk0r   = (float*)(ws + off); off += wpk_b;
    float* wpk1f   = (float*)(ws + off); off += wpk_b;
    float* wpk1r   = (float*)(ws + off); off += wpk_b;
    float* h_state = (float*)(ws + off); off += state_b;
    float* c_state = (float*)(ws + off); off += state_b;
    _Float16* gxf  = (_Float16*)(ws + off); off += gx_b;
    _Float16* gxr  = (_Float16*)(ws + off); off += gx_b;

    // ---- precompute (5 launches) ----
    embed_cvt<<<TT * BB, 128, 0, stream>>>(x, emb, xs2);
    wcvt2<<<dim3(512, 2), 128, 0, stream>>>(w_ih_l0, w_ih_l0r, EE, 128, w2l0f, w2l0r);
    wcvt2<<<dim3(512, 2), 256, 0, stream>>>(w_ih_l1, w_ih_l1r, K1, 256, w2l1f, w2l1r);
    bias2<<<8, 256, 0, stream>>>(b_ih_l0, b_hh_l0, b_ih_l0r, b_hh_l0r,
                                 b_ih_l1, b_hh_l1, b_ih_l1r, b_hh_l1r, biasl0);
    whh_pack4<<<dim3(128, 4), 128, 0, stream>>>(w_hh_l0, w_hh_l0r, w_hh_l1, w_hh_l1r, wpk0f);

    // ---- layer 0: whole-T gemm (fp16 gx, L3-resident) + one lstm dispatch ----
    gemm_mfma<128><<<dim3(8, TT), 256, 0, stream>>>(xs2, w2l0f, biasl0, gxf, gxr);
    lstm_chunk<<<256, 512, 0, stream>>>(gxf, gxr, wpk0f, wpk0r,
                                        h_state, c_state, x1_2, nullptr);
    // ---- layer 1 ----
    gemm_mfma<256><<<dim3(8, TT), 256, 0, stream>>>(x1_2, w2l1f, biasl1, gxf, gxr);
    lstm_chunk<<<256, 512, 0, stream>>>(gxf, gxr, wpk1f, wpk1r,
                                        h_state, c_state, nullptr, h_state);
    // ---- FC head ----
    fc_kernel<<<2, 192, 0, stream>>>(h_state, fc_w, fc_b, out);
}